// Round 11
// baseline (178.466 us; speedup 1.0000x reference)
//
#include <hip/hip_runtime.h>

#define Bc 8
#define Tc 8
#define Cc 32
#define Hc 16
#define Wc 28
#define NHc 4
#define DKc 8
#define HWc (Hc*Wc)                  // 448
#define INV_SCALE 0.35355339059327373f
#define LN_EPSc 1e-5f

typedef _Float16 half8  __attribute__((ext_vector_type(8)));
typedef _Float16 half2v __attribute__((ext_vector_type(2)));

union H8 { half8 v; half2v h2[4]; };

// Workspace layouts:
//   Qh    : [bh][t][hw]        half8    (LN'd, pre-scaled by INV_SCALE, fp16)
//   Kh    : [bh][s][hw]        half8    (fp16)
//   Vh    : [bh][s][hw]        half8    (fp16)
//   Tpart : [bh][s][t][hw]     half8    (fp16 partials) = 4*N5 floats
//   LM    : [bh][s][t][hw]     float2   (l = sum exp, m = max score)

// ---------------------------------------------------------------------------
// Kernel 1: QKV projection + fused LayerNorm of q.
// grid = 256, 448 threads.  blk = head*64 + bt (XCD co-location of the
// 4 blocks sharing one bt slice of first/x).
// ---------------------------------------------------------------------------
__global__ __launch_bounds__(448) void qkv_ln_kernel(
    const float* __restrict__ first, const float* __restrict__ x,
    const float* __restrict__ Wq, const float* __restrict__ Wk,
    const float* __restrict__ Wv,
    const float* __restrict__ gamma, const float* __restrict__ beta,
    half8* __restrict__ Qh, half8* __restrict__ Kh, half8* __restrict__ Vh)
{
    int blk  = blockIdx.x;           // head*64 + bt
    int head = blk >> 6;
    int bt   = blk & 63;             // b*T + t
    int t    = bt % Tc;
    int b    = bt / Tc;
    int tid  = threadIdx.x;          // h*W + w

    const float* fp = first + (size_t)bt * Cc * HWc + tid;
    const float* xp = x     + (size_t)bt * Cc * HWc + tid;
    float fv[Cc], xv[Cc];
#pragma unroll
    for (int c = 0; c < Cc; ++c) { fv[c] = fp[c*HWc]; xv[c] = xp[c*HWc]; }

    float qv[DKc], kv[DKc], vv[DKc];
#pragma unroll
    for (int dk = 0; dk < DKc; ++dk) {
        int o = head*DKc + dk;       // lane-uniform -> scalar loads of weights
        float aq = 0.f, ak = 0.f, av = 0.f;
#pragma unroll
        for (int c = 0; c < Cc; ++c) {
            aq = fmaf(Wq[o*Cc+c], fv[c], aq);
            ak = fmaf(Wk[o*Cc+c], xv[c], ak);
            av = fmaf(Wv[o*Cc+c], xv[c], av);
        }
        qv[dk] = aq; kv[dk] = ak; vv[dk] = av;
    }

    int bh = b*NHc + head;
    half8 kh, vh;
#pragma unroll
    for (int dk = 0; dk < DKc; ++dk) {
        kh[dk] = (_Float16)kv[dk];
        vh[dk] = (_Float16)vv[dk];
    }
    Kh[((size_t)bh*Tc + t)*HWc + tid] = kh;
    Vh[((size_t)bh*Tc + t)*HWc + tid] = vh;

    // LayerNorm over (DK,H,W) = 3584 values for this (b,t,head)
    float s1 = 0.f, s2 = 0.f;
#pragma unroll
    for (int dk = 0; dk < DKc; ++dk) { s1 += qv[dk]; s2 += qv[dk]*qv[dk]; }
#pragma unroll
    for (int off = 32; off >= 1; off >>= 1) {
        s1 += __shfl_down(s1, off, 64);
        s2 += __shfl_down(s2, off, 64);
    }
    __shared__ float r1[8], r2[8];
    int wid = tid >> 6, lane = tid & 63;
    if (lane == 0) { r1[wid] = s1; r2[wid] = s2; }
    __syncthreads();
    float S1 = 0.f, S2 = 0.f;
#pragma unroll
    for (int wv2 = 0; wv2 < 7; ++wv2) { S1 += r1[wv2]; S2 += r2[wv2]; }
    const float invN = 1.f / (float)(DKc * HWc);
    float mu   = S1 * invN;
    float var  = S2 * invN - mu*mu;
    float rstd = rsqrtf(var + LN_EPSc);

    half8 qh;
#pragma unroll
    for (int dk = 0; dk < DKc; ++dk) {
        float gg = gamma[dk*HWc + tid];
        float bb = beta [dk*HWc + tid];
        qh[dk] = (_Float16)(((qv[dk] - mu) * rstd * gg + bb) * INV_SCALE);
    }
    Qh[((size_t)bh*Tc + t)*HWc + tid] = qh;
}

// ---------------------------------------------------------------------------
// Kernel 2: attention.  t_batch = 4, grid = 512 single-item blocks.
// Stride-256 complementary-head pairing (R8): blk and blk+256 co-resident on
// one CU; blk<256 -> heads {0,1}, blk>=256 -> heads {3,2} (heavy+light mix).
// fp16 K AND V in LDS: 2 ds_read_b128 per offset (was 3).  Scores via
// v_dot2_f32_f16 chains; V converted fp16->fp32 once per offset (shared
// across the 4 t); fp32 accumulate.  Zero-slot masking for invalid dx.
// ---------------------------------------------------------------------------
__global__ __launch_bounds__(448, 4) void attn_kernel(
    const half8* __restrict__ Qh, const half8* __restrict__ Kh,
    const half8* __restrict__ Vh,
    half8* __restrict__ Tpart, float2* __restrict__ LMpart)
{
    int blk = blockIdx.x;
    int p   = blk >> 8;              // pairing half
    int i   = blk & 255;
    int b   = i >> 5;
    int ha  = (i >> 4) & 1;
    int s   = (i >> 1) & 7;
    int th  = i & 1;

    int head = p ? (3 - ha) : ha;
    int dil  = 2*head + 1;           // {1,3,5,7}
    int bh   = b*NHc + head;
    int t0   = th*4;

    int tid = threadIdx.x;           // h*W + w
    int w = tid % Wc;
    int h = tid / Wc;

    __shared__ half8 sK[HWc+1];      // 7184 B (+ zero slot)
    __shared__ half8 sV[HWc+1];      // 7184 B

    sK[tid] = Kh[((size_t)bh*Tc + s)*HWc + tid];
    sV[tid] = Vh[((size_t)bh*Tc + s)*HWc + tid];
    if (tid == 0) {
        half8 z = {};
        sK[HWc] = z;
        sV[HWc] = z;
    }

    H8 q[4];
#pragma unroll
    for (int j = 0; j < 4; ++j)
        q[j].v = Qh[((size_t)bh*Tc + (t0+j))*HWc + tid];

    float a[4][DKc];
    float l[4], m[4];
#pragma unroll
    for (int j = 0; j < 4; ++j) {
#pragma unroll
        for (int k = 0; k < DKc; ++k) a[j][k] = 0.f;
        l[j] = 0.f; m[j] = -1e30f;
    }

    __syncthreads();

    for (int dy = -3; dy <= 3; ++dy) {
        int hy = h + dy*dil;
        if ((unsigned)hy >= (unsigned)Hc) continue;   // exec-mask row skip
        int rowbase = hy*Wc;
#pragma unroll
        for (int dx = -3; dx <= 3; ++dx) {
            int wx = w + dx*dil;
            bool cv = (unsigned)wx < (unsigned)Wc;
            int idx = cv ? (rowbase + wx) : HWc;      // zero slot if invalid
            float bias = cv ? 0.f : -1e30f;
            H8 k; k.v = sK[idx];
            H8 vv; vv.v = sV[idx];
            float vf[DKc];
#pragma unroll
            for (int e = 0; e < DKc; ++e) vf[e] = (float)vv.v[e];
#pragma unroll
            for (int j = 0; j < 4; ++j) {
                float sc = __builtin_amdgcn_fdot2(q[j].h2[0], k.h2[0],
                           __builtin_amdgcn_fdot2(q[j].h2[1], k.h2[1],
                           __builtin_amdgcn_fdot2(q[j].h2[2], k.h2[2],
                           __builtin_amdgcn_fdot2(q[j].h2[3], k.h2[3],
                                                  0.f, false), false), false), false);
                float msc = sc + bias;
                m[j] = fmaxf(m[j], msc);
                l[j] += __expf(msc);
                // invalid lanes: k=0 -> sc=0 -> zero contribution
#pragma unroll
                for (int e = 0; e < DKc; ++e)
                    a[j][e] = fmaf(sc, vf[e], a[j][e]);
            }
        }
    }

    half8*  tp  = Tpart  + (size_t)(bh*Tc + s)*Tc*HWc + tid;
    float2* lmp = LMpart + (size_t)(bh*Tc + s)*Tc*HWc + tid;
#pragma unroll
    for (int j = 0; j < 4; ++j) {
        half8 hv;
#pragma unroll
        for (int e = 0; e < DKc; ++e) hv[e] = (_Float16)a[j][e];
        tp [(t0+j)*HWc] = hv;
        lmp[(t0+j)*HWc] = make_float2(l[j], m[j]);
    }
}

// ---------------------------------------------------------------------------
// Kernel 3: fused combine + output projection, de-duplicated.
// grid = 256 blocks: blk = bt*4 + hq (hw-quarter of 112 positions).
// Phase A: 448 threads = 4 heads x 112 hw -- each reduces one head's
//   8 channels over s into LDS (read each Tpart/LM element exactly ONCE).
// Phase B: 448 threads = 4 og x 112 hw -- project 8 channels from the
//   LDS-shared 32-vector.  mvs padded to 33 floats/row (conflict-free).
// ---------------------------------------------------------------------------
__global__ __launch_bounds__(448) void outproj_kernel(
    const half8* __restrict__ Tpart, const float2* __restrict__ LMpart,
    const float* __restrict__ Wo, float* __restrict__ out)
{
    int blk = blockIdx.x;            // bt*4 + hq
    int hq  = blk & 3;
    int bt  = blk >> 2;
    int b   = bt >> 3, t = bt & 7;
    int u   = threadIdx.x;

    __shared__ float mvs[112][33];   // padded: bank = (hwq+c)%32, conflict-free
    __shared__ float ps [112][5];    // per-(hwq, head) max softmax prob

    int head = u / 112;              // phase A role
    int hwq  = u % 112;
    int hw   = hq*112 + hwq;
    int bh   = b*NHc + head;

    float acc[DKc];
#pragma unroll
    for (int j = 0; j < DKc; ++j) acc[j] = 0.f;
    float lsum = 0.f, mmax = -1e30f;
#pragma unroll
    for (int s = 0; s < Tc; ++s) {
        size_t base = (size_t)((bh*Tc + s)*Tc + t)*HWc + hw;
        half8 tv = Tpart[base];
#pragma unroll
        for (int j = 0; j < DKc; ++j) acc[j] += (float)tv[j];
        float2 lm = LMpart[base];
        lsum += lm.x; mmax = fmaxf(mmax, lm.y);
    }
#pragma unroll
    for (int j = 0; j < DKc; ++j) mvs[hwq][head*DKc + j] = acc[j];
    ps[hwq][head] = __expf(mmax) / lsum;
    __syncthreads();

    int og = u / 112;                // phase B role (same hwq)
    float MS = fmaxf(fmaxf(ps[hwq][0], ps[hwq][1]),
                     fmaxf(ps[hwq][2], ps[hwq][3]));
    float o8[8];
#pragma unroll
    for (int i = 0; i < 8; ++i) o8[i] = 0.f;
#pragma unroll
    for (int c = 0; c < Cc; ++c) {
        float mv = mvs[hwq][c];
#pragma unroll
        for (int i = 0; i < 8; ++i)
            o8[i] = fmaf(Wo[(og*8 + i)*Cc + c], mv, o8[i]);
    }
#pragma unroll
    for (int i = 0; i < 8; ++i)
        out[((size_t)bt*Cc + og*8 + i)*HWc + hw] = o8[i] * MS;
}

// ---------------------------------------------------------------------------
extern "C" void kernel_launch(void* const* d_in, const int* in_sizes, int n_in,
                              void* d_out, int out_size, void* d_ws, size_t ws_size,
                              hipStream_t stream) {
    const float* first = (const float*)d_in[0];
    const float* x     = (const float*)d_in[1];
    const float* Wq    = (const float*)d_in[2];
    const float* Wk    = (const float*)d_in[3];
    const float* Wv    = (const float*)d_in[4];
    const float* Wo    = (const float*)d_in[5];
    const float* g     = (const float*)d_in[6];
    const float* bta   = (const float*)d_in[7];
    float* out = (float*)d_out;

    float* ws = (float*)d_ws;
    const size_t N5 = (size_t)Bc*NHc*Tc*HWc*DKc;    // 917504 elements
    half8*  Qh  = (half8*)ws;                        // N5 halves = N5/2 floats
    half8*  Kh  = (half8*)(ws + N5/2);               // N5/2 floats
    half8*  Vh  = (half8*)(ws + N5);                 // N5/2 floats
    half8*  Tp  = (half8*)(ws + 3*N5/2);             // 917504 half8 = 4*N5 floats
    float2* LMp = (float2*)(ws + 3*N5/2 + 4*N5);     // 2*N5 floats
    // total: 15*N5/2 floats ~= 27.5 MB

    qkv_ln_kernel <<<Bc*Tc*NHc, 448, 0, stream>>>(first, x, Wq, Wk, Wv, g, bta, Qh, Kh, Vh);
    attn_kernel   <<<512,       448, 0, stream>>>(Qh, Kh, Vh, Tp, LMp);
    outproj_kernel<<<256,       448, 0, stream>>>(Tp, LMp, Wo, out);
}

// Round 12
// 118.314 us; speedup vs baseline: 1.5084x; 1.5084x over previous
//
#include <hip/hip_runtime.h>

#define Bc 8
#define Tc 8
#define Cc 32
#define Hc 16
#define Wc 28
#define NHc 4
#define DKc 8
#define HWc (Hc*Wc)                  // 448
#define INV_SCALE 0.35355339059327373f
#define LN_EPSc 1e-5f

typedef _Float16 half8  __attribute__((ext_vector_type(8)));
typedef _Float16 half2v __attribute__((ext_vector_type(2)));

union H8 { half8 v; half2v h2[4]; };

// Workspace layouts:
//   Qh    : [bh][t][hw]        half8    (LN'd, pre-scaled by INV_SCALE, fp16)
//   Kh    : [bh][s][hw]        half8    (fp16)
//   Vh    : [bh][s][hw]        half8    (fp16)
//   Tpart : [bh][s][t][hw]     half8    (fp16 partials) = 4*N5 floats
//   LM    : [bh][s][t][hw]     float2   (l = sum exp, m = max score)
//
// NOTE (R11 post-mortem): accumulators MUST be named float4s, not indexed
// 2-D arrays -- float a[4][8] was demoted to scratch (195 MB HBM writes).

// ---------------------------------------------------------------------------
// Kernel 1: QKV projection + fused LayerNorm of q.
// grid = 256, 448 threads.  blk = head*64 + bt (XCD co-location of the
// 4 blocks sharing one bt slice of first/x).
// ---------------------------------------------------------------------------
__global__ __launch_bounds__(448) void qkv_ln_kernel(
    const float* __restrict__ first, const float* __restrict__ x,
    const float* __restrict__ Wq, const float* __restrict__ Wk,
    const float* __restrict__ Wv,
    const float* __restrict__ gamma, const float* __restrict__ beta,
    half8* __restrict__ Qh, half8* __restrict__ Kh, half8* __restrict__ Vh)
{
    int blk  = blockIdx.x;           // head*64 + bt
    int head = blk >> 6;
    int bt   = blk & 63;             // b*T + t
    int t    = bt % Tc;
    int b    = bt / Tc;
    int tid  = threadIdx.x;          // h*W + w

    const float* fp = first + (size_t)bt * Cc * HWc + tid;
    const float* xp = x     + (size_t)bt * Cc * HWc + tid;
    float fv[Cc], xv[Cc];
#pragma unroll
    for (int c = 0; c < Cc; ++c) { fv[c] = fp[c*HWc]; xv[c] = xp[c*HWc]; }

    float qv[DKc], kv[DKc], vv[DKc];
#pragma unroll
    for (int dk = 0; dk < DKc; ++dk) {
        int o = head*DKc + dk;       // lane-uniform -> scalar loads of weights
        float aq = 0.f, ak = 0.f, av = 0.f;
#pragma unroll
        for (int c = 0; c < Cc; ++c) {
            aq = fmaf(Wq[o*Cc+c], fv[c], aq);
            ak = fmaf(Wk[o*Cc+c], xv[c], ak);
            av = fmaf(Wv[o*Cc+c], xv[c], av);
        }
        qv[dk] = aq; kv[dk] = ak; vv[dk] = av;
    }

    int bh = b*NHc + head;
    half8 kh, vh;
#pragma unroll
    for (int dk = 0; dk < DKc; ++dk) {
        kh[dk] = (_Float16)kv[dk];
        vh[dk] = (_Float16)vv[dk];
    }
    Kh[((size_t)bh*Tc + t)*HWc + tid] = kh;
    Vh[((size_t)bh*Tc + t)*HWc + tid] = vh;

    // LayerNorm over (DK,H,W) = 3584 values for this (b,t,head)
    float s1 = 0.f, s2 = 0.f;
#pragma unroll
    for (int dk = 0; dk < DKc; ++dk) { s1 += qv[dk]; s2 += qv[dk]*qv[dk]; }
#pragma unroll
    for (int off = 32; off >= 1; off >>= 1) {
        s1 += __shfl_down(s1, off, 64);
        s2 += __shfl_down(s2, off, 64);
    }
    __shared__ float r1[8], r2[8];
    int wid = tid >> 6, lane = tid & 63;
    if (lane == 0) { r1[wid] = s1; r2[wid] = s2; }
    __syncthreads();
    float S1 = 0.f, S2 = 0.f;
#pragma unroll
    for (int wv2 = 0; wv2 < 7; ++wv2) { S1 += r1[wv2]; S2 += r2[wv2]; }
    const float invN = 1.f / (float)(DKc * HWc);
    float mu   = S1 * invN;
    float var  = S2 * invN - mu*mu;
    float rstd = rsqrtf(var + LN_EPSc);

    half8 qh;
#pragma unroll
    for (int dk = 0; dk < DKc; ++dk) {
        float gg = gamma[dk*HWc + tid];
        float bb = beta [dk*HWc + tid];
        qh[dk] = (_Float16)(((qv[dk] - mu) * rstd * gg + bb) * INV_SCALE);
    }
    Qh[((size_t)bh*Tc + t)*HWc + tid] = qh;
}

// ---------------------------------------------------------------------------
// Kernel 2: attention.  t_batch = 4, grid = 512 single-item blocks.
// Stride-256 complementary-head pairing: blk and blk+256 co-resident on one
// CU; blk<256 -> heads {0,1}, blk>=256 -> heads {3,2} (heavy+light mix).
// fp16 K AND V in LDS: 2 ds_read_b128 per offset.  Scores via
// v_dot2_f32_f16 chains; V converted to two named float4s per offset
// (shared across the 4 t); fp32 accumulate in named float4 registers.
// Zero-slot masking for invalid dx.
// ---------------------------------------------------------------------------
__global__ __launch_bounds__(448, 4) void attn_kernel(
    const half8* __restrict__ Qh, const half8* __restrict__ Kh,
    const half8* __restrict__ Vh,
    half8* __restrict__ Tpart, float2* __restrict__ LMpart)
{
    int blk = blockIdx.x;
    int p   = blk >> 8;              // pairing half
    int i   = blk & 255;
    int b   = i >> 5;
    int ha  = (i >> 4) & 1;
    int s   = (i >> 1) & 7;
    int th  = i & 1;

    int head = p ? (3 - ha) : ha;
    int dil  = 2*head + 1;           // {1,3,5,7}
    int bh   = b*NHc + head;
    int t0   = th*4;

    int tid = threadIdx.x;           // h*W + w
    int w = tid % Wc;
    int h = tid / Wc;

    __shared__ half8 sK[HWc+1];      // 7184 B (+ zero slot)
    __shared__ half8 sV[HWc+1];      // 7184 B

    sK[tid] = Kh[((size_t)bh*Tc + s)*HWc + tid];
    sV[tid] = Vh[((size_t)bh*Tc + s)*HWc + tid];
    if (tid == 0) {
        half8 z = {};
        sK[HWc] = z;
        sV[HWc] = z;
    }

    H8 q0, q1, q2, q3;
    {
        const half8* qb = Qh + ((size_t)bh*Tc + t0)*HWc + tid;
        q0.v = qb[0*HWc]; q1.v = qb[1*HWc]; q2.v = qb[2*HWc]; q3.v = qb[3*HWc];
    }

    float4 a00 = {0,0,0,0}, a01 = {0,0,0,0};
    float4 a10 = {0,0,0,0}, a11 = {0,0,0,0};
    float4 a20 = {0,0,0,0}, a21 = {0,0,0,0};
    float4 a30 = {0,0,0,0}, a31 = {0,0,0,0};
    float l0 = 0.f, l1 = 0.f, l2 = 0.f, l3 = 0.f;
    float m0 = -1e30f, m1 = -1e30f, m2 = -1e30f, m3 = -1e30f;

    __syncthreads();

    for (int dy = -3; dy <= 3; ++dy) {
        int hy = h + dy*dil;
        if ((unsigned)hy >= (unsigned)Hc) continue;   // exec-mask row skip
        int rowbase = hy*Wc;
#pragma unroll
        for (int dx = -3; dx <= 3; ++dx) {
            int wx = w + dx*dil;
            bool cv = (unsigned)wx < (unsigned)Wc;
            int idx = cv ? (rowbase + wx) : HWc;      // zero slot if invalid
            float bias = cv ? 0.f : -1e30f;
            H8 k; k.v = sK[idx];
            half8 vh = sV[idx];
            float4 v0 = make_float4((float)vh[0], (float)vh[1],
                                    (float)vh[2], (float)vh[3]);
            float4 v1 = make_float4((float)vh[4], (float)vh[5],
                                    (float)vh[6], (float)vh[7]);

#define ATTN_STEP(qq, aa0, aa1, ll, mm)                                       \
            {                                                                 \
                float sc = __builtin_amdgcn_fdot2(qq.h2[0], k.h2[0],          \
                           __builtin_amdgcn_fdot2(qq.h2[1], k.h2[1],          \
                           __builtin_amdgcn_fdot2(qq.h2[2], k.h2[2],          \
                           __builtin_amdgcn_fdot2(qq.h2[3], k.h2[3],          \
                                                  0.f, false), false), false), false); \
                float msc = sc + bias;                                        \
                mm = fmaxf(mm, msc);                                          \
                ll += __expf(msc);                                            \
                aa0.x = fmaf(sc, v0.x, aa0.x);                                \
                aa0.y = fmaf(sc, v0.y, aa0.y);                                \
                aa0.z = fmaf(sc, v0.z, aa0.z);                                \
                aa0.w = fmaf(sc, v0.w, aa0.w);                                \
                aa1.x = fmaf(sc, v1.x, aa1.x);                                \
                aa1.y = fmaf(sc, v1.y, aa1.y);                                \
                aa1.z = fmaf(sc, v1.z, aa1.z);                                \
                aa1.w = fmaf(sc, v1.w, aa1.w);                                \
            }
            ATTN_STEP(q0, a00, a01, l0, m0)
            ATTN_STEP(q1, a10, a11, l1, m1)
            ATTN_STEP(q2, a20, a21, l2, m2)
            ATTN_STEP(q3, a30, a31, l3, m3)
#undef ATTN_STEP
        }
    }

    half8*  tp  = Tpart  + (size_t)(bh*Tc + s)*Tc*HWc + tid;
    float2* lmp = LMpart + (size_t)(bh*Tc + s)*Tc*HWc + tid;
#define STORE_T(j, aa0, aa1, ll, mm)                                          \
    {                                                                         \
        half8 hv;                                                             \
        hv[0] = (_Float16)aa0.x; hv[1] = (_Float16)aa0.y;                     \
        hv[2] = (_Float16)aa0.z; hv[3] = (_Float16)aa0.w;                     \
        hv[4] = (_Float16)aa1.x; hv[5] = (_Float16)aa1.y;                     \
        hv[6] = (_Float16)aa1.z; hv[7] = (_Float16)aa1.w;                     \
        tp [(t0+j)*HWc] = hv;                                                 \
        lmp[(t0+j)*HWc] = make_float2(ll, mm);                                \
    }
    STORE_T(0, a00, a01, l0, m0)
    STORE_T(1, a10, a11, l1, m1)
    STORE_T(2, a20, a21, l2, m2)
    STORE_T(3, a30, a31, l3, m3)
#undef STORE_T
}

// ---------------------------------------------------------------------------
// Kernel 3: fused combine + output projection, de-duplicated.
// grid = 256 blocks: blk = bt*4 + hq (hw-quarter of 112 positions).
// Phase A: 448 threads = 4 heads x 112 hw -- each reduces one head's
//   8 channels over s into LDS (read each Tpart/LM element exactly ONCE).
// Phase B: 448 threads = 4 og x 112 hw -- project 8 channels from the
//   LDS-shared 32-vector.  mvs padded to 33 floats/row (conflict-free).
// ---------------------------------------------------------------------------
__global__ __launch_bounds__(448) void outproj_kernel(
    const half8* __restrict__ Tpart, const float2* __restrict__ LMpart,
    const float* __restrict__ Wo, float* __restrict__ out)
{
    int blk = blockIdx.x;            // bt*4 + hq
    int hq  = blk & 3;
    int bt  = blk >> 2;
    int b   = bt >> 3, t = bt & 7;
    int u   = threadIdx.x;

    __shared__ float mvs[112][33];   // padded
    __shared__ float ps [112][5];

    int head = u / 112;              // phase A role
    int hwq  = u % 112;
    int hw   = hq*112 + hwq;
    int bh   = b*NHc + head;

    float4 ac0 = {0,0,0,0}, ac1 = {0,0,0,0};
    float lsum = 0.f, mmax = -1e30f;
#pragma unroll
    for (int s = 0; s < Tc; ++s) {
        size_t base = (size_t)((bh*Tc + s)*Tc + t)*HWc + hw;
        half8 tv = Tpart[base];
        ac0.x += (float)tv[0]; ac0.y += (float)tv[1];
        ac0.z += (float)tv[2]; ac0.w += (float)tv[3];
        ac1.x += (float)tv[4]; ac1.y += (float)tv[5];
        ac1.z += (float)tv[6]; ac1.w += (float)tv[7];
        float2 lm = LMpart[base];
        lsum += lm.x; mmax = fmaxf(mmax, lm.y);
    }
    mvs[hwq][head*DKc+0] = ac0.x; mvs[hwq][head*DKc+1] = ac0.y;
    mvs[hwq][head*DKc+2] = ac0.z; mvs[hwq][head*DKc+3] = ac0.w;
    mvs[hwq][head*DKc+4] = ac1.x; mvs[hwq][head*DKc+5] = ac1.y;
    mvs[hwq][head*DKc+6] = ac1.z; mvs[hwq][head*DKc+7] = ac1.w;
    ps[hwq][head] = __expf(mmax) / lsum;
    __syncthreads();

    int og = u / 112;                // phase B role (same hwq)
    float MS = fmaxf(fmaxf(ps[hwq][0], ps[hwq][1]),
                     fmaxf(ps[hwq][2], ps[hwq][3]));
    float o0=0.f,o1=0.f,o2=0.f,o3=0.f,o4=0.f,o5=0.f,o6=0.f,o7=0.f;
#pragma unroll
    for (int c = 0; c < Cc; ++c) {
        float mv = mvs[hwq][c];
        o0 = fmaf(Wo[(og*8+0)*Cc + c], mv, o0);
        o1 = fmaf(Wo[(og*8+1)*Cc + c], mv, o1);
        o2 = fmaf(Wo[(og*8+2)*Cc + c], mv, o2);
        o3 = fmaf(Wo[(og*8+3)*Cc + c], mv, o3);
        o4 = fmaf(Wo[(og*8+4)*Cc + c], mv, o4);
        o5 = fmaf(Wo[(og*8+5)*Cc + c], mv, o5);
        o6 = fmaf(Wo[(og*8+6)*Cc + c], mv, o6);
        o7 = fmaf(Wo[(og*8+7)*Cc + c], mv, o7);
    }
    size_t ob = (size_t)bt*Cc*HWc + hw;
    out[ob + (og*8+0)*HWc] = o0 * MS;
    out[ob + (og*8+1)*HWc] = o1 * MS;
    out[ob + (og*8+2)*HWc] = o2 * MS;
    out[ob + (og*8+3)*HWc] = o3 * MS;
    out[ob + (og*8+4)*HWc] = o4 * MS;
    out[ob + (og*8+5)*HWc] = o5 * MS;
    out[ob + (og*8+6)*HWc] = o6 * MS;
    out[ob + (og*8+7)*HWc] = o7 * MS;
}

// ---------------------------------------------------------------------------
extern "C" void kernel_launch(void* const* d_in, const int* in_sizes, int n_in,
                              void* d_out, int out_size, void* d_ws, size_t ws_size,
                              hipStream_t stream) {
    const float* first = (const float*)d_in[0];
    const float* x     = (const float*)d_in[1];
    const float* Wq    = (const float*)d_in[2];
    const float* Wk    = (const float*)d_in[3];
    const float* Wv    = (const float*)d_in[4];
    const float* Wo    = (const float*)d_in[5];
    const float* g     = (const float*)d_in[6];
    const float* bta   = (const float*)d_in[7];
    float* out = (float*)d_out;

    float* ws = (float*)d_ws;
    const size_t N5 = (size_t)Bc*NHc*Tc*HWc*DKc;    // 917504 elements
    half8*  Qh  = (half8*)ws;                        // N5/2 floats
    half8*  Kh  = (half8*)(ws + N5/2);               // N5/2 floats
    half8*  Vh  = (half8*)(ws + N5);                 // N5/2 floats
    half8*  Tp  = (half8*)(ws + 3*N5/2);             // 4*N5 floats
    float2* LMp = (float2*)(ws + 3*N5/2 + 4*N5);     // 2*N5 floats
    // total: 15*N5/2 floats ~= 27.5 MB

    qkv_ln_kernel <<<Bc*Tc*NHc, 448, 0, stream>>>(first, x, Wq, Wk, Wv, g, bta, Qh, Kh, Vh);
    attn_kernel   <<<512,       448, 0, stream>>>(Qh, Kh, Vh, Tp, LMp);
    outproj_kernel<<<256,       448, 0, stream>>>(Tp, LMp, Wo, out);
}

// Round 13
// 114.166 us; speedup vs baseline: 1.5632x; 1.0363x over previous
//
#include <hip/hip_runtime.h>

#define Bc 8
#define Tc 8
#define Cc 32
#define Hc 16
#define Wc 28
#define NHc 4
#define DKc 8
#define HWc (Hc*Wc)                  // 448
#define INV_SCALE 0.35355339059327373f
#define LN_EPSc 1e-5f

typedef _Float16 half8  __attribute__((ext_vector_type(8)));
typedef _Float16 half2v __attribute__((ext_vector_type(2)));

union H8 { half8 v; half2v h2[4]; };

// Workspace layouts:
//   Qh    : [bh][t][hw]        half8    (LN'd, pre-scaled by INV_SCALE, fp16)
//   Kh    : [bh][s][hw]        half8    (fp16)
//   Vh    : [bh][s][hw]        half8    (fp16)
//   Tpart : [bh][s][t][hw]     half8    (fp16 partials) = 4*N5 floats
//   LM    : [bh][s][t][hw]     float2   (l = sum exp, m = max score)
//
// R11 lesson: accumulators must be NAMED registers (no indexed 2-D arrays —
// scratch demotion costs 195 MB of HBM traffic).
// R12 lesson: fp16 V only pays if never converted — so accumulate in fp16
// with v_pk_fma_f16 (per-s partials <= 49 terms; s-sum stays fp32 downstream).

// ---------------------------------------------------------------------------
// Kernel 1: QKV projection + fused LayerNorm of q.
// grid = 256, 448 threads.  blk = head*64 + bt (XCD co-location of the
// 4 blocks sharing one bt slice of first/x).
// ---------------------------------------------------------------------------
__global__ __launch_bounds__(448) void qkv_ln_kernel(
    const float* __restrict__ first, const float* __restrict__ x,
    const float* __restrict__ Wq, const float* __restrict__ Wk,
    const float* __restrict__ Wv,
    const float* __restrict__ gamma, const float* __restrict__ beta,
    half8* __restrict__ Qh, half8* __restrict__ Kh, half8* __restrict__ Vh)
{
    int blk  = blockIdx.x;           // head*64 + bt
    int head = blk >> 6;
    int bt   = blk & 63;             // b*T + t
    int t    = bt % Tc;
    int b    = bt / Tc;
    int tid  = threadIdx.x;          // h*W + w

    const float* fp = first + (size_t)bt * Cc * HWc + tid;
    const float* xp = x     + (size_t)bt * Cc * HWc + tid;
    float fv[Cc], xv[Cc];
#pragma unroll
    for (int c = 0; c < Cc; ++c) { fv[c] = fp[c*HWc]; xv[c] = xp[c*HWc]; }

    float qv[DKc], kv[DKc], vv[DKc];
#pragma unroll
    for (int dk = 0; dk < DKc; ++dk) {
        int o = head*DKc + dk;       // lane-uniform -> scalar loads of weights
        float aq = 0.f, ak = 0.f, av = 0.f;
#pragma unroll
        for (int c = 0; c < Cc; ++c) {
            aq = fmaf(Wq[o*Cc+c], fv[c], aq);
            ak = fmaf(Wk[o*Cc+c], xv[c], ak);
            av = fmaf(Wv[o*Cc+c], xv[c], av);
        }
        qv[dk] = aq; kv[dk] = ak; vv[dk] = av;
    }

    int bh = b*NHc + head;
    half8 kh, vh;
#pragma unroll
    for (int dk = 0; dk < DKc; ++dk) {
        kh[dk] = (_Float16)kv[dk];
        vh[dk] = (_Float16)vv[dk];
    }
    Kh[((size_t)bh*Tc + t)*HWc + tid] = kh;
    Vh[((size_t)bh*Tc + t)*HWc + tid] = vh;

    // LayerNorm over (DK,H,W) = 3584 values for this (b,t,head)
    float s1 = 0.f, s2 = 0.f;
#pragma unroll
    for (int dk = 0; dk < DKc; ++dk) { s1 += qv[dk]; s2 += qv[dk]*qv[dk]; }
#pragma unroll
    for (int off = 32; off >= 1; off >>= 1) {
        s1 += __shfl_down(s1, off, 64);
        s2 += __shfl_down(s2, off, 64);
    }
    __shared__ float r1[8], r2[8];
    int wid = tid >> 6, lane = tid & 63;
    if (lane == 0) { r1[wid] = s1; r2[wid] = s2; }
    __syncthreads();
    float S1 = 0.f, S2 = 0.f;
#pragma unroll
    for (int wv2 = 0; wv2 < 7; ++wv2) { S1 += r1[wv2]; S2 += r2[wv2]; }
    const float invN = 1.f / (float)(DKc * HWc);
    float mu   = S1 * invN;
    float var  = S2 * invN - mu*mu;
    float rstd = rsqrtf(var + LN_EPSc);

    half8 qh;
#pragma unroll
    for (int dk = 0; dk < DKc; ++dk) {
        float gg = gamma[dk*HWc + tid];
        float bb = beta [dk*HWc + tid];
        qh[dk] = (_Float16)(((qv[dk] - mu) * rstd * gg + bb) * INV_SCALE);
    }
    Qh[((size_t)bh*Tc + t)*HWc + tid] = qh;
}

// ---------------------------------------------------------------------------
// Kernel 2: attention.  t_batch = 4, grid = 512 single-item blocks.
// Stride-256 complementary-head pairing: blk and blk+256 co-resident on one
// CU; blk<256 -> heads {0,1}, blk>=256 -> heads {3,2} (heavy+light mix).
// fp16 K AND V in LDS (2 ds_read_b128/offset).  Scores via v_dot2_f32_f16;
// accumulate in fp16 with v_pk_fma_f16 (score broadcast to half8) -- no V
// conversion, direct half8 partial store.  l/m stay fp32.
// ---------------------------------------------------------------------------
__global__ __launch_bounds__(448, 4) void attn_kernel(
    const half8* __restrict__ Qh, const half8* __restrict__ Kh,
    const half8* __restrict__ Vh,
    half8* __restrict__ Tpart, float2* __restrict__ LMpart)
{
    int blk = blockIdx.x;
    int p   = blk >> 8;              // pairing half
    int i   = blk & 255;
    int b   = i >> 5;
    int ha  = (i >> 4) & 1;
    int s   = (i >> 1) & 7;
    int th  = i & 1;

    int head = p ? (3 - ha) : ha;
    int dil  = 2*head + 1;           // {1,3,5,7}
    int bh   = b*NHc + head;
    int t0   = th*4;

    int tid = threadIdx.x;           // h*W + w
    int w = tid % Wc;
    int h = tid / Wc;

    __shared__ half8 sK[HWc+1];      // 7184 B (+ zero slot)
    __shared__ half8 sV[HWc+1];      // 7184 B

    sK[tid] = Kh[((size_t)bh*Tc + s)*HWc + tid];
    sV[tid] = Vh[((size_t)bh*Tc + s)*HWc + tid];
    if (tid == 0) {
        half8 z = {};
        sK[HWc] = z;
        sV[HWc] = z;
    }

    H8 q0, q1, q2, q3;
    {
        const half8* qb = Qh + ((size_t)bh*Tc + t0)*HWc + tid;
        q0.v = qb[0*HWc]; q1.v = qb[1*HWc]; q2.v = qb[2*HWc]; q3.v = qb[3*HWc];
    }

    half8 a0 = {}, a1 = {}, a2 = {}, a3 = {};
    float l0 = 0.f, l1 = 0.f, l2 = 0.f, l3 = 0.f;
    float m0 = -1e30f, m1 = -1e30f, m2 = -1e30f, m3 = -1e30f;

    __syncthreads();

    for (int dy = -3; dy <= 3; ++dy) {
        int hy = h + dy*dil;
        if ((unsigned)hy >= (unsigned)Hc) continue;   // exec-mask row skip
        int rowbase = hy*Wc;
#pragma unroll
        for (int dx = -3; dx <= 3; ++dx) {
            int wx = w + dx*dil;
            bool cv = (unsigned)wx < (unsigned)Wc;
            int idx = cv ? (rowbase + wx) : HWc;      // zero slot if invalid
            float bias = cv ? 0.f : -1e30f;
            H8 k; k.v = sK[idx];
            half8 vh = sV[idx];

#define ATTN_STEP(qq, acc, ll, mm)                                            \
            {                                                                 \
                float sc = __builtin_amdgcn_fdot2(qq.h2[0], k.h2[0],          \
                           __builtin_amdgcn_fdot2(qq.h2[1], k.h2[1],          \
                           __builtin_amdgcn_fdot2(qq.h2[2], k.h2[2],          \
                           __builtin_amdgcn_fdot2(qq.h2[3], k.h2[3],          \
                                                  0.f, false), false), false), false); \
                float msc = sc + bias;                                        \
                mm = fmaxf(mm, msc);                                          \
                ll += __expf(msc);                                            \
                _Float16 sh = (_Float16)sc;                                   \
                half8 scb = { sh, sh, sh, sh, sh, sh, sh, sh };               \
                acc += scb * vh;   /* 4x v_pk_fma_f16; invalid: k=0 -> sc=0 */ \
            }
            ATTN_STEP(q0, a0, l0, m0)
            ATTN_STEP(q1, a1, l1, m1)
            ATTN_STEP(q2, a2, l2, m2)
            ATTN_STEP(q3, a3, l3, m3)
#undef ATTN_STEP
        }
    }

    half8*  tp  = Tpart  + (size_t)(bh*Tc + s)*Tc*HWc + tid;
    float2* lmp = LMpart + (size_t)(bh*Tc + s)*Tc*HWc + tid;
    tp [(t0+0)*HWc] = a0;  lmp[(t0+0)*HWc] = make_float2(l0, m0);
    tp [(t0+1)*HWc] = a1;  lmp[(t0+1)*HWc] = make_float2(l1, m1);
    tp [(t0+2)*HWc] = a2;  lmp[(t0+2)*HWc] = make_float2(l2, m2);
    tp [(t0+3)*HWc] = a3;  lmp[(t0+3)*HWc] = make_float2(l3, m3);
}

// ---------------------------------------------------------------------------
// Kernel 3: fused combine + output projection, de-duplicated.
// grid = 256 blocks: blk = bt*4 + hq (hw-quarter of 112 positions).
// Phase A: 448 threads = 4 heads x 112 hw -- reduce one head's 8 channels
//   over s (fp32) into LDS; each Tpart/LM element read exactly once.
// Phase B: 448 threads = 4 og x 112 hw -- project from LDS-shared 32-vector.
// ---------------------------------------------------------------------------
__global__ __launch_bounds__(448) void outproj_kernel(
    const half8* __restrict__ Tpart, const float2* __restrict__ LMpart,
    const float* __restrict__ Wo, float* __restrict__ out)
{
    int blk = blockIdx.x;            // bt*4 + hq
    int hq  = blk & 3;
    int bt  = blk >> 2;
    int b   = bt >> 3, t = bt & 7;
    int u   = threadIdx.x;

    __shared__ float mvs[112][33];   // padded
    __shared__ float ps [112][5];

    int head = u / 112;              // phase A role
    int hwq  = u % 112;
    int hw   = hq*112 + hwq;
    int bh   = b*NHc + head;

    float4 ac0 = {0,0,0,0}, ac1 = {0,0,0,0};
    float lsum = 0.f, mmax = -1e30f;
#pragma unroll
    for (int s = 0; s < Tc; ++s) {
        size_t base = (size_t)((bh*Tc + s)*Tc + t)*HWc + hw;
        half8 tv = Tpart[base];
        ac0.x += (float)tv[0]; ac0.y += (float)tv[1];
        ac0.z += (float)tv[2]; ac0.w += (float)tv[3];
        ac1.x += (float)tv[4]; ac1.y += (float)tv[5];
        ac1.z += (float)tv[6]; ac1.w += (float)tv[7];
        float2 lm = LMpart[base];
        lsum += lm.x; mmax = fmaxf(mmax, lm.y);
    }
    mvs[hwq][head*DKc+0] = ac0.x; mvs[hwq][head*DKc+1] = ac0.y;
    mvs[hwq][head*DKc+2] = ac0.z; mvs[hwq][head*DKc+3] = ac0.w;
    mvs[hwq][head*DKc+4] = ac1.x; mvs[hwq][head*DKc+5] = ac1.y;
    mvs[hwq][head*DKc+6] = ac1.z; mvs[hwq][head*DKc+7] = ac1.w;
    ps[hwq][head] = __expf(mmax) / lsum;
    __syncthreads();

    int og = u / 112;                // phase B role (same hwq)
    float MS = fmaxf(fmaxf(ps[hwq][0], ps[hwq][1]),
                     fmaxf(ps[hwq][2], ps[hwq][3]));
    float o0=0.f,o1=0.f,o2=0.f,o3=0.f,o4=0.f,o5=0.f,o6=0.f,o7=0.f;
#pragma unroll
    for (int c = 0; c < Cc; ++c) {
        float mv = mvs[hwq][c];
        o0 = fmaf(Wo[(og*8+0)*Cc + c], mv, o0);
        o1 = fmaf(Wo[(og*8+1)*Cc + c], mv, o1);
        o2 = fmaf(Wo[(og*8+2)*Cc + c], mv, o2);
        o3 = fmaf(Wo[(og*8+3)*Cc + c], mv, o3);
        o4 = fmaf(Wo[(og*8+4)*Cc + c], mv, o4);
        o5 = fmaf(Wo[(og*8+5)*Cc + c], mv, o5);
        o6 = fmaf(Wo[(og*8+6)*Cc + c], mv, o6);
        o7 = fmaf(Wo[(og*8+7)*Cc + c], mv, o7);
    }
    size_t ob = (size_t)bt*Cc*HWc + hw;
    out[ob + (og*8+0)*HWc] = o0 * MS;
    out[ob + (og*8+1)*HWc] = o1 * MS;
    out[ob + (og*8+2)*HWc] = o2 * MS;
    out[ob + (og*8+3)*HWc] = o3 * MS;
    out[ob + (og*8+4)*HWc] = o4 * MS;
    out[ob + (og*8+5)*HWc] = o5 * MS;
    out[ob + (og*8+6)*HWc] = o6 * MS;
    out[ob + (og*8+7)*HWc] = o7 * MS;
}

// ---------------------------------------------------------------------------
extern "C" void kernel_launch(void* const* d_in, const int* in_sizes, int n_in,
                              void* d_out, int out_size, void* d_ws, size_t ws_size,
                              hipStream_t stream) {
    const float* first = (const float*)d_in[0];
    const float* x     = (const float*)d_in[1];
    const float* Wq    = (const float*)d_in[2];
    const float* Wk    = (const float*)d_in[3];
    const float* Wv    = (const float*)d_in[4];
    const float* Wo    = (const float*)d_in[5];
    const float* g     = (const float*)d_in[6];
    const float* bta   = (const float*)d_in[7];
    float* out = (float*)d_out;

    float* ws = (float*)d_ws;
    const size_t N5 = (size_t)Bc*NHc*Tc*HWc*DKc;    // 917504 elements
    half8*  Qh  = (half8*)ws;                        // N5/2 floats
    half8*  Kh  = (half8*)(ws + N5/2);               // N5/2 floats
    half8*  Vh  = (half8*)(ws + N5);                 // N5/2 floats
    half8*  Tp  = (half8*)(ws + 3*N5/2);             // 4*N5 floats
    float2* LMp = (float2*)(ws + 3*N5/2 + 4*N5);     // 2*N5 floats
    // total: 15*N5/2 floats ~= 27.5 MB

    qkv_ln_kernel <<<Bc*Tc*NHc, 448, 0, stream>>>(first, x, Wq, Wk, Wv, g, bta, Qh, Kh, Vh);
    attn_kernel   <<<512,       448, 0, stream>>>(Qh, Kh, Vh, Tp, LMp);
    outproj_kernel<<<256,       448, 0, stream>>>(Tp, LMp, Wo, out);
}